// Round 1
// baseline (859.293 us; speedup 1.0000x reference)
//
#include <hip/hip_runtime.h>
#include <hip/hip_bf16.h>
#include <stdint.h>
#include <math.h>

#define NN 16384
#define DD 256
#define MARGIN_F 0.2f

#define BM 128
#define BN 128
#define BK 128

typedef __attribute__((ext_vector_type(8))) short bf16x8;
typedef __attribute__((ext_vector_type(4))) float f32x4;

__device__ inline short f2bf(float f) {
    __hip_bfloat16 h = __float2bfloat16(f);
    return *reinterpret_cast<short*>(&h);
}

// float atomic max via int/uint atomics (handles any sign, init = -inf)
__device__ inline void atomicMaxF(float* addr, float val) {
    if (val >= 0.0f) {
        atomicMax(reinterpret_cast<int*>(addr), __float_as_int(val));
    } else {
        atomicMin(reinterpret_cast<unsigned int*>(addr), __float_as_uint(val));
    }
}

// ---------------- prep: diag + init rowmax/colmax ----------------
__global__ void prep_kernel(const float* __restrict__ imgs,
                            const float* __restrict__ caps,
                            float* __restrict__ diag,
                            float* __restrict__ rowmax,
                            float* __restrict__ colmax) {
    int i = blockIdx.x;
    int l = threadIdx.x;  // 0..63
    const float4* a = reinterpret_cast<const float4*>(imgs + (size_t)i * DD);
    const float4* b = reinterpret_cast<const float4*>(caps + (size_t)i * DD);
    float4 av = a[l];
    float4 bv = b[l];
    float s = av.x * bv.x + av.y * bv.y + av.z * bv.z + av.w * bv.w;
    #pragma unroll
    for (int off = 32; off > 0; off >>= 1) s += __shfl_down(s, off);
    if (l == 0) {
        diag[i] = s;
        rowmax[i] = -INFINITY;
        colmax[i] = -INFINITY;
    }
}

// ---------------- main: tiled bf16 MFMA score + running max ----------------
__global__ __launch_bounds__(256) void score_max_kernel(
    const float* __restrict__ imgs, const float* __restrict__ caps,
    const float* __restrict__ diag,
    float* __restrict__ rowmax, float* __restrict__ colmax) {

    __shared__ short As[BM * BK];   // 32 KB
    __shared__ short Bs[BN * BK];   // 32 KB

    const int brow = blockIdx.y * BM;
    const int bcol = blockIdx.x * BN;
    const int t    = threadIdx.x;
    const int wid  = t >> 6;
    const int lane = t & 63;
    const int wr   = wid >> 1;   // wave row 0..1  (64-row half)
    const int wc   = wid & 1;    // wave col 0..1  (64-col half)
    const int rg   = lane >> 4;  // 0..3
    const int cl   = lane & 15;  // 0..15

    f32x4 acc[4][4];
    #pragma unroll
    for (int m = 0; m < 4; ++m)
        #pragma unroll
        for (int n = 0; n < 4; ++n)
            acc[m][n] = (f32x4){0.f, 0.f, 0.f, 0.f};

    for (int kk = 0; kk < DD; kk += BK) {
        // ---- stage f32 -> bf16 into LDS (XOR-swizzled rows) ----
        #pragma unroll
        for (int i = 0; i < 8; ++i) {
            int c   = t + (i << 8);      // 0..2047
            int row = c >> 4;            // 0..127
            int ck  = c & 15;            // chunk of 8 along K
            int gk  = kk + (ck << 3);

            const float4* pa = reinterpret_cast<const float4*>(
                imgs + (size_t)(brow + row) * DD + gk);
            float4 a0 = pa[0], a1 = pa[1];
            bf16x8 avv;
            avv[0] = f2bf(a0.x); avv[1] = f2bf(a0.y);
            avv[2] = f2bf(a0.z); avv[3] = f2bf(a0.w);
            avv[4] = f2bf(a1.x); avv[5] = f2bf(a1.y);
            avv[6] = f2bf(a1.z); avv[7] = f2bf(a1.w);
            int byteo = row * (BK * 2) + (ck << 4);
            byteo ^= (row & 7) << 4;
            *reinterpret_cast<bf16x8*>(reinterpret_cast<char*>(As) + byteo) = avv;

            const float4* pb = reinterpret_cast<const float4*>(
                caps + (size_t)(bcol + row) * DD + gk);
            float4 b0 = pb[0], b1 = pb[1];
            bf16x8 bvv;
            bvv[0] = f2bf(b0.x); bvv[1] = f2bf(b0.y);
            bvv[2] = f2bf(b0.z); bvv[3] = f2bf(b0.w);
            bvv[4] = f2bf(b1.x); bvv[5] = f2bf(b1.y);
            bvv[6] = f2bf(b1.z); bvv[7] = f2bf(b1.w);
            *reinterpret_cast<bf16x8*>(reinterpret_cast<char*>(Bs) + byteo) = bvv;
        }
        __syncthreads();

        // ---- MFMA over this K-chunk (4 k-steps of 32) ----
        #pragma unroll
        for (int ks = 0; ks < 4; ++ks) {
            int lk = (ks << 5) + (rg << 3);   // k within chunk, 8 contiguous
            bf16x8 af[4], bfr[4];
            #pragma unroll
            for (int m = 0; m < 4; ++m) {
                int r = wr * 64 + m * 16 + cl;
                int byteo = r * (BK * 2) + (lk << 1);
                byteo ^= (r & 7) << 4;
                af[m] = *reinterpret_cast<bf16x8*>(
                    reinterpret_cast<char*>(As) + byteo);
            }
            #pragma unroll
            for (int n = 0; n < 4; ++n) {
                int r = wc * 64 + n * 16 + cl;
                int byteo = r * (BK * 2) + (lk << 1);
                byteo ^= (r & 7) << 4;
                bfr[n] = *reinterpret_cast<bf16x8*>(
                    reinterpret_cast<char*>(Bs) + byteo);
            }
            #pragma unroll
            for (int m = 0; m < 4; ++m)
                #pragma unroll
                for (int n = 0; n < 4; ++n)
                    acc[m][n] = __builtin_amdgcn_mfma_f32_16x16x32_bf16(
                        af[m], bfr[n], acc[m][n], 0, 0, 0);
        }
        __syncthreads();
    }

    // ---- diagonal fix: s[i,i] = -diag[i] ----
    if (brow + wr * 64 == bcol + wc * 64) {
        #pragma unroll
        for (int m = 0; m < 4; ++m)
            #pragma unroll
            for (int r = 0; r < 4; ++r) {
                int li = m * 16 + rg * 4 + r;   // local row in 64-span
                // matches local col n*16+cl  ->  n = li>>4, cl == li&15
                int n = li >> 4;
                if (cl == (li & 15)) {
                    acc[m][n][r] = -diag[brow + wr * 64 + li];
                }
            }
    }

    // ---- row maxes (max over this wave's 64 cols) ----
    #pragma unroll
    for (int m = 0; m < 4; ++m) {
        #pragma unroll
        for (int r = 0; r < 4; ++r) {
            float v = fmaxf(fmaxf(acc[m][0][r], acc[m][1][r]),
                            fmaxf(acc[m][2][r], acc[m][3][r]));
            v = fmaxf(v, __shfl_xor(v, 1));
            v = fmaxf(v, __shfl_xor(v, 2));
            v = fmaxf(v, __shfl_xor(v, 4));
            v = fmaxf(v, __shfl_xor(v, 8));
            if (cl == 0) {
                int gi = brow + wr * 64 + m * 16 + rg * 4 + r;
                atomicMaxF(&rowmax[gi], v);
            }
        }
    }

    // ---- col maxes (max over this wave's 64 rows) ----
    #pragma unroll
    for (int n = 0; n < 4; ++n) {
        float v = -INFINITY;
        #pragma unroll
        for (int m = 0; m < 4; ++m)
            #pragma unroll
            for (int r = 0; r < 4; ++r)
                v = fmaxf(v, acc[m][n][r]);
        v = fmaxf(v, __shfl_xor(v, 16));
        v = fmaxf(v, __shfl_xor(v, 32));
        if (rg == 0) {
            int gj = bcol + wc * 64 + n * 16 + cl;
            atomicMaxF(&colmax[gj], v);
        }
    }
}

// ---------------- finalize: hinge + total sum ----------------
__global__ void finalize_kernel(const float* __restrict__ diag,
                                const float* __restrict__ rowmax,
                                const float* __restrict__ colmax,
                                float* __restrict__ out) {
    __shared__ float red[256];
    int t = threadIdx.x;
    float s = 0.f;
    for (int idx = t; idx < 2 * NN; idx += 256) {
        int i = idx & (NN - 1);
        float mx = (idx < NN) ? colmax[i] : rowmax[i];
        s += fmaxf(mx + (MARGIN_F - diag[i]), 0.f);
    }
    red[t] = s;
    __syncthreads();
    for (int off = 128; off > 0; off >>= 1) {
        if (t < off) red[t] += red[t + off];
        __syncthreads();
    }
    if (t == 0) out[0] = red[0];
}

extern "C" void kernel_launch(void* const* d_in, const int* in_sizes, int n_in,
                              void* d_out, int out_size, void* d_ws, size_t ws_size,
                              hipStream_t stream) {
    const float* imgs = reinterpret_cast<const float*>(d_in[0]);
    const float* caps = reinterpret_cast<const float*>(d_in[1]);

    float* diag   = reinterpret_cast<float*>(d_ws);
    float* rowmax = diag + NN;
    float* colmax = rowmax + NN;

    prep_kernel<<<NN, 64, 0, stream>>>(imgs, caps, diag, rowmax, colmax);

    dim3 grid(NN / BN, NN / BM);
    score_max_kernel<<<grid, 256, 0, stream>>>(imgs, caps, diag, rowmax, colmax);

    finalize_kernel<<<1, 256, 0, stream>>>(diag, rowmax, colmax,
                                           reinterpret_cast<float*>(d_out));
}

// Round 2
// 559.307 us; speedup vs baseline: 1.5364x; 1.5364x over previous
//
#include <hip/hip_runtime.h>
#include <hip/hip_bf16.h>
#include <stdint.h>
#include <math.h>

#define NN 16384
#define DD 256
#define MARGIN_F 0.2f

#define BM 128
#define BN 128
#define BK 32

typedef __attribute__((ext_vector_type(8))) short bf16x8;
typedef __attribute__((ext_vector_type(4))) float f32x4;

__device__ inline short f2bf(float f) {
    __hip_bfloat16 h = __float2bfloat16(f);
    return *reinterpret_cast<short*>(&h);
}

__device__ inline void gload16(const void* g, void* l) {
    __builtin_amdgcn_global_load_lds(
        (const __attribute__((address_space(1))) void*)g,
        (__attribute__((address_space(3))) void*)l, 16, 0, 0);
}

// float atomic max via int/uint atomics (init = -inf)
__device__ inline void atomicMaxF(float* addr, float val) {
    if (val >= 0.0f) {
        atomicMax(reinterpret_cast<int*>(addr), __float_as_int(val));
    } else {
        atomicMin(reinterpret_cast<unsigned int*>(addr), __float_as_uint(val));
    }
}

// ---------------- convert f32 -> bf16 (one-time prepass) ----------------
__global__ __launch_bounds__(256) void convert_kernel(
    const float* __restrict__ in, short* __restrict__ out) {
    int i = blockIdx.x * 256 + threadIdx.x;   // handles 8 elems
    const float4* p = reinterpret_cast<const float4*>(in) + (size_t)i * 2;
    float4 a = p[0], b = p[1];
    bf16x8 v;
    v[0] = f2bf(a.x); v[1] = f2bf(a.y); v[2] = f2bf(a.z); v[3] = f2bf(a.w);
    v[4] = f2bf(b.x); v[5] = f2bf(b.y); v[6] = f2bf(b.z); v[7] = f2bf(b.w);
    reinterpret_cast<bf16x8*>(out)[i] = v;
}

// ---------------- prep: diag + init rowmax/colmax ----------------
__global__ void prep_kernel(const float* __restrict__ imgs,
                            const float* __restrict__ caps,
                            float* __restrict__ diag,
                            float* __restrict__ rowmax,
                            float* __restrict__ colmax) {
    int i = blockIdx.x;
    int l = threadIdx.x;  // 0..63
    const float4* a = reinterpret_cast<const float4*>(imgs + (size_t)i * DD);
    const float4* b = reinterpret_cast<const float4*>(caps + (size_t)i * DD);
    float4 av = a[l];
    float4 bv = b[l];
    float s = av.x * bv.x + av.y * bv.y + av.z * bv.z + av.w * bv.w;
    #pragma unroll
    for (int off = 32; off > 0; off >>= 1) s += __shfl_down(s, off);
    if (l == 0) {
        diag[i] = s;
        rowmax[i] = -INFINITY;
        colmax[i] = -INFINITY;
    }
}

// ---------------- main: m97-style bf16 MFMA tile + running max ----------------
__global__ __launch_bounds__(256) void score_max_kernel(
    const short* __restrict__ imgsb, const short* __restrict__ capsb,
    const float* __restrict__ diag,
    float* __restrict__ rowmax, float* __restrict__ colmax) {

    __shared__ short As[BM * BK];   // 8 KB, row-major [128][32], chunk-swizzled
    __shared__ short Bs[BN * BK];   // 8 KB

    // XCD-aware bijective swizzle (16384 % 8 == 0): contiguous panel per XCD
    const int bid = blockIdx.x;
    const int cpx = gridDim.x >> 3;
    const int swz = (bid & 7) * cpx + (bid >> 3);
    const int by  = swz >> 7;          // 128 col-tiles per row-panel
    const int bx  = swz & 127;
    const int brow = by * BM;
    const int bcol = bx * BN;

    const int t    = threadIdx.x;
    const int wid  = t >> 6;
    const int lane = t & 63;
    const int wr   = wid >> 1;   // wave row 0..1 (64-row half)
    const int wc   = wid & 1;    // wave col 0..1 (64-col half)
    const int rg   = lane >> 4;  // 0..3
    const int cl   = lane & 15;  // 0..15

    f32x4 acc[4][4];
    #pragma unroll
    for (int m = 0; m < 4; ++m)
        #pragma unroll
        for (int n = 0; n < 4; ++n)
            acc[m][n] = (f32x4){0.f, 0.f, 0.f, 0.f};

    // staging geometry: wave `wid` fills two 16-row regions (wid*2+i)
    // linear slot (row, c): holds global chunk c ^ (row&3) ^ ((row>>2)&3)
    const int srow = lane >> 2;                 // 0..15 within region
    const int gch  = (lane & 3) ^ ((lane >> 2) & 3) ^ ((lane >> 4) & 3);

    for (int kk = 0; kk < DD; kk += BK) {
        #pragma unroll
        for (int i = 0; i < 2; ++i) {
            int reg = wid * 2 + i;
            int row = reg * 16 + srow;
            gload16(imgsb + (size_t)(brow + row) * DD + kk + gch * 8,
                    As + reg * 512);
            gload16(capsb + (size_t)(bcol + row) * DD + kk + gch * 8,
                    Bs + reg * 512);
        }
        __syncthreads();

        bf16x8 af[4], bfr[4];
        #pragma unroll
        for (int m = 0; m < 4; ++m) {
            int r  = wr * 64 + m * 16 + cl;
            int ch = rg ^ (r & 3) ^ ((r >> 2) & 3);
            af[m] = *reinterpret_cast<const bf16x8*>(
                reinterpret_cast<const char*>(As) + r * 64 + ch * 16);
        }
        #pragma unroll
        for (int n = 0; n < 4; ++n) {
            int r  = wc * 64 + n * 16 + cl;
            int ch = rg ^ (r & 3) ^ ((r >> 2) & 3);
            bfr[n] = *reinterpret_cast<const bf16x8*>(
                reinterpret_cast<const char*>(Bs) + r * 64 + ch * 16);
        }
        #pragma unroll
        for (int m = 0; m < 4; ++m)
            #pragma unroll
            for (int n = 0; n < 4; ++n)
                acc[m][n] = __builtin_amdgcn_mfma_f32_16x16x32_bf16(
                    af[m], bfr[n], acc[m][n], 0, 0, 0);
        __syncthreads();
    }

    // ---- diagonal fix: s[i,i] = -diag[i] ----
    if (brow + wr * 64 == bcol + wc * 64) {
        #pragma unroll
        for (int m = 0; m < 4; ++m)
            #pragma unroll
            for (int r = 0; r < 4; ++r) {
                int li = m * 16 + rg * 4 + r;   // local row in 64-span
                int n = li >> 4;
                if (cl == (li & 15)) {
                    acc[m][n][r] = -diag[brow + wr * 64 + li];
                }
            }
    }

    // ---- row maxes (max over this wave's 64 cols) ----
    #pragma unroll
    for (int m = 0; m < 4; ++m) {
        #pragma unroll
        for (int r = 0; r < 4; ++r) {
            float v = fmaxf(fmaxf(acc[m][0][r], acc[m][1][r]),
                            fmaxf(acc[m][2][r], acc[m][3][r]));
            v = fmaxf(v, __shfl_xor(v, 1));
            v = fmaxf(v, __shfl_xor(v, 2));
            v = fmaxf(v, __shfl_xor(v, 4));
            v = fmaxf(v, __shfl_xor(v, 8));
            if (cl == 0) {
                int gi = brow + wr * 64 + m * 16 + rg * 4 + r;
                atomicMaxF(&rowmax[gi], v);
            }
        }
    }

    // ---- col maxes (max over this wave's 64 rows) ----
    #pragma unroll
    for (int n = 0; n < 4; ++n) {
        float v = -INFINITY;
        #pragma unroll
        for (int m = 0; m < 4; ++m)
            #pragma unroll
            for (int r = 0; r < 4; ++r)
                v = fmaxf(v, acc[m][n][r]);
        v = fmaxf(v, __shfl_xor(v, 16));
        v = fmaxf(v, __shfl_xor(v, 32));
        if (rg == 0) {
            int gj = bcol + wc * 64 + n * 16 + cl;
            atomicMaxF(&colmax[gj], v);
        }
    }
}

// ---------------- finalize: hinge + total sum ----------------
__global__ void finalize_kernel(const float* __restrict__ diag,
                                const float* __restrict__ rowmax,
                                const float* __restrict__ colmax,
                                float* __restrict__ out) {
    __shared__ float red[256];
    int t = threadIdx.x;
    float s = 0.f;
    for (int idx = t; idx < 2 * NN; idx += 256) {
        int i = idx & (NN - 1);
        float mx = (idx < NN) ? colmax[i] : rowmax[i];
        s += fmaxf(mx + (MARGIN_F - diag[i]), 0.f);
    }
    red[t] = s;
    __syncthreads();
    for (int off = 128; off > 0; off >>= 1) {
        if (t < off) red[t] += red[t + off];
        __syncthreads();
    }
    if (t == 0) out[0] = red[0];
}

extern "C" void kernel_launch(void* const* d_in, const int* in_sizes, int n_in,
                              void* d_out, int out_size, void* d_ws, size_t ws_size,
                              hipStream_t stream) {
    const float* imgs = reinterpret_cast<const float*>(d_in[0]);
    const float* caps = reinterpret_cast<const float*>(d_in[1]);

    float* diag   = reinterpret_cast<float*>(d_ws);
    float* rowmax = diag + NN;
    float* colmax = rowmax + NN;
    short* imgsb  = reinterpret_cast<short*>(colmax + NN);
    short* capsb  = imgsb + (size_t)NN * DD;

    // prepass: bf16 conversion (NN*DD/8 threads each)
    convert_kernel<<<(NN * DD / 8 + 255) / 256, 256, 0, stream>>>(imgs, imgsb);
    convert_kernel<<<(NN * DD / 8 + 255) / 256, 256, 0, stream>>>(caps, capsb);
    prep_kernel<<<NN, 64, 0, stream>>>(imgs, caps, diag, rowmax, colmax);

    score_max_kernel<<<(NN / BM) * (NN / BN), 256, 0, stream>>>(
        imgsb, capsb, diag, rowmax, colmax);

    finalize_kernel<<<1, 256, 0, stream>>>(diag, rowmax, colmax,
                                           reinterpret_cast<float*>(d_out));
}

// Round 3
// 186.736 us; speedup vs baseline: 4.6016x; 2.9952x over previous
//
#include <hip/hip_runtime.h>
#include <hip/hip_bf16.h>
#include <stdint.h>
#include <math.h>

#define NN 16384
#define DD 256
#define MARGIN_F 0.2f

typedef __attribute__((ext_vector_type(8))) short bf16x8;
typedef __attribute__((ext_vector_type(4))) float f32x4;

__device__ inline short f2bf(float f) {
    __hip_bfloat16 h = __float2bfloat16(f);
    return *reinterpret_cast<short*>(&h);
}

__device__ inline void gload16(const void* g, void* l) {
    __builtin_amdgcn_global_load_lds(
        (const __attribute__((address_space(1))) void*)g,
        (__attribute__((address_space(3))) void*)l, 16, 0, 0);
}

// float atomic max via int/uint atomics (init = -inf)
__device__ inline void atomicMaxF(float* addr, float val) {
    if (val >= 0.0f) {
        atomicMax(reinterpret_cast<int*>(addr), __float_as_int(val));
    } else {
        atomicMin(reinterpret_cast<unsigned int*>(addr), __float_as_uint(val));
    }
}

// ---------------- convert f32 -> bf16 (one-time prepass) ----------------
__global__ __launch_bounds__(256) void convert_kernel(
    const float* __restrict__ in, short* __restrict__ out) {
    int i = blockIdx.x * 256 + threadIdx.x;   // handles 8 elems
    const float4* p = reinterpret_cast<const float4*>(in) + (size_t)i * 2;
    float4 a = p[0], b = p[1];
    bf16x8 v;
    v[0] = f2bf(a.x); v[1] = f2bf(a.y); v[2] = f2bf(a.z); v[3] = f2bf(a.w);
    v[4] = f2bf(b.x); v[5] = f2bf(b.y); v[6] = f2bf(b.z); v[7] = f2bf(b.w);
    reinterpret_cast<bf16x8*>(out)[i] = v;
}

// ---------------- prep: diag + init rowmax/colmax ----------------
__global__ void prep_kernel(const float* __restrict__ imgs,
                            const float* __restrict__ caps,
                            float* __restrict__ diag,
                            float* __restrict__ rowmax,
                            float* __restrict__ colmax) {
    int i = blockIdx.x;
    int l = threadIdx.x;  // 0..63
    const float4* a = reinterpret_cast<const float4*>(imgs + (size_t)i * DD);
    const float4* b = reinterpret_cast<const float4*>(caps + (size_t)i * DD);
    float4 av = a[l];
    float4 bv = b[l];
    float s = av.x * bv.x + av.y * bv.y + av.z * bv.z + av.w * bv.w;
    #pragma unroll
    for (int off = 32; off > 0; off >>= 1) s += __shfl_down(s, off);
    if (l == 0) {
        diag[i] = s;
        rowmax[i] = -INFINITY;
        colmax[i] = -INFINITY;
    }
}

// ---------------- main: A-resident strip kernel ----------------
// 512 blocks = 128 row-panels x 4 col-strips (4096 cols = 64 chunks of 64).
// A panel (128x256) staged once -> registers; B chunks double-buffered.
__global__ __launch_bounds__(256, 2) void score_max_kernel(
    const short* __restrict__ imgsb, const short* __restrict__ capsb,
    const float* __restrict__ diag,
    float* __restrict__ rowmax, float* __restrict__ colmax) {

    __shared__ char lds[65536];   // A panel first, then 2x32KB B buffers

    const int bid   = blockIdx.x;
    const int panel = bid >> 2;
    const int strip = bid & 3;
    const int brow  = panel << 7;    // 128-row panel
    const int scol  = strip << 12;   // 4096-col strip

    const int t    = threadIdx.x;
    const int wid  = t >> 6;
    const int lane = t & 63;
    const int wr   = wid >> 1;   // 0..1: 64-row half
    const int wc   = wid & 1;    // 0..1: 32-col half of 64-col chunk
    const int rg   = lane >> 4;  // 0..3
    const int cl   = lane & 15;  // 0..15

    // ---- stage A panel: 128 rows x 32 slots of 16B, chunk-swizzled ----
    {
        const int cs = t & 31;       // slot within row
        const int r0 = t >> 5;       // base row 0..7
        const int co = ((cs ^ (r0 & 7)) << 3);   // (row&7) invariant across i
        const short* src = imgsb + (((size_t)(brow + r0)) << 8) + co;
        #pragma unroll
        for (int i = 0; i < 16; ++i)
            gload16(src + ((size_t)i << 11), lds + t * 16 + i * 4096);
    }
    __syncthreads();

    // ---- A fragments to registers: af[m][ks], 128 VGPRs ----
    bf16x8 af[4][8];
    #pragma unroll
    for (int m = 0; m < 4; ++m) {
        const int row = wr * 64 + m * 16 + cl;
        const char* rb = lds + row * 512;
        const int sw = row & 7;
        #pragma unroll
        for (int ks = 0; ks < 8; ++ks) {
            const int k8 = (ks << 2) + rg;
            af[m][ks] = *reinterpret_cast<const bf16x8*>(rb + ((k8 ^ sw) << 4));
        }
    }
    __syncthreads();   // everyone done reading A before B overwrites

    // ---- B staging geometry (row&7 invariant across i) ----
    const int bcs = t & 31;
    const int br0 = t >> 5;                       // 0..7
    const int bco = ((bcs ^ (br0 & 7)) << 3);

    #define STAGEB(bo, cb) {                                                   \
        const short* s_ = capsb + (((size_t)((cb) + br0)) << 8) + bco;         \
        _Pragma("unroll")                                                      \
        for (int i_ = 0; i_ < 8; ++i_)                                         \
            gload16(s_ + ((size_t)i_ << 11), lds + (bo) + t * 16 + i_ * 4096); \
    }

    float rmx[4][4];
    #pragma unroll
    for (int m = 0; m < 4; ++m)
        #pragma unroll
        for (int r = 0; r < 4; ++r) rmx[m][r] = -INFINITY;

    STAGEB(0, scol);
    __syncthreads();

    for (int h = 0; h < 64; ++h) {
        const int cb = scol + h * 64;
        const char* cur = lds + ((h & 1) << 15);
        if (h + 1 < 64) { STAGEB(((h + 1) & 1) << 15, cb + 64); }

        f32x4 acc[4][2];
        #pragma unroll
        for (int m = 0; m < 4; ++m) {
            acc[m][0] = (f32x4){0.f, 0.f, 0.f, 0.f};
            acc[m][1] = (f32x4){0.f, 0.f, 0.f, 0.f};
        }

        #pragma unroll
        for (int ks = 0; ks < 8; ++ks) {
            const int k8 = (ks << 2) + rg;
            const int r0 = wc * 32 + cl;        // n=0 col-row
            const int r1 = r0 + 16;             // n=1 col-row
            bf16x8 bf0 = *reinterpret_cast<const bf16x8*>(
                cur + r0 * 512 + ((k8 ^ (r0 & 7)) << 4));
            bf16x8 bf1 = *reinterpret_cast<const bf16x8*>(
                cur + r1 * 512 + ((k8 ^ (r1 & 7)) << 4));
            #pragma unroll
            for (int m = 0; m < 4; ++m) {
                acc[m][0] = __builtin_amdgcn_mfma_f32_16x16x32_bf16(
                    af[m][ks], bf0, acc[m][0], 0, 0, 0);
                acc[m][1] = __builtin_amdgcn_mfma_f32_16x16x32_bf16(
                    af[m][ks], bf1, acc[m][1], 0, 0, 0);
            }
        }

        // ---- diagonal fix (at most 2 chunks per block) ----
        if (cb < brow + 128 && cb + 64 > brow) {
            #pragma unroll
            for (int m = 0; m < 4; ++m)
                #pragma unroll
                for (int r = 0; r < 4; ++r) {
                    const int i = brow + wr * 64 + m * 16 + (rg << 2) + r;
                    const int d = i - cb - wc * 32;
                    #pragma unroll
                    for (int n = 0; n < 2; ++n)
                        if (d == n * 16 + cl) acc[m][n][r] = -diag[i];
                }
        }

        // ---- running row-max (registers, no shuffles) ----
        #pragma unroll
        for (int m = 0; m < 4; ++m)
            #pragma unroll
            for (int r = 0; r < 4; ++r)
                rmx[m][r] = fmaxf(rmx[m][r],
                                  fmaxf(acc[m][0][r], acc[m][1][r]));

        // ---- col-max for this chunk ----
        #pragma unroll
        for (int n = 0; n < 2; ++n) {
            float v = acc[0][n][0];
            #pragma unroll
            for (int m = 0; m < 4; ++m)
                #pragma unroll
                for (int r = 0; r < 4; ++r)
                    v = fmaxf(v, acc[m][n][r]);
            v = fmaxf(v, __shfl_xor(v, 16));
            v = fmaxf(v, __shfl_xor(v, 32));
            if (rg == 0)
                atomicMaxF(&colmax[cb + wc * 32 + n * 16 + cl], v);
        }
        __syncthreads();
    }

    // ---- row-max writeout (once per block) ----
    #pragma unroll
    for (int m = 0; m < 4; ++m)
        #pragma unroll
        for (int r = 0; r < 4; ++r) {
            float v = rmx[m][r];
            v = fmaxf(v, __shfl_xor(v, 1));
            v = fmaxf(v, __shfl_xor(v, 2));
            v = fmaxf(v, __shfl_xor(v, 4));
            v = fmaxf(v, __shfl_xor(v, 8));
            if (cl == 0)
                atomicMaxF(&rowmax[brow + wr * 64 + m * 16 + (rg << 2) + r], v);
        }
    #undef STAGEB
}

// ---------------- finalize: hinge + total sum ----------------
__global__ void finalize_kernel(const float* __restrict__ diag,
                                const float* __restrict__ rowmax,
                                const float* __restrict__ colmax,
                                float* __restrict__ out) {
    __shared__ float red[256];
    int t = threadIdx.x;
    float s = 0.f;
    for (int idx = t; idx < 2 * NN; idx += 256) {
        int i = idx & (NN - 1);
        float mx = (idx < NN) ? colmax[i] : rowmax[i];
        s += fmaxf(mx + (MARGIN_F - diag[i]), 0.f);
    }
    red[t] = s;
    __syncthreads();
    for (int off = 128; off > 0; off >>= 1) {
        if (t < off) red[t] += red[t + off];
        __syncthreads();
    }
    if (t == 0) out[0] = red[0];
}

extern "C" void kernel_launch(void* const* d_in, const int* in_sizes, int n_in,
                              void* d_out, int out_size, void* d_ws, size_t ws_size,
                              hipStream_t stream) {
    const float* imgs = reinterpret_cast<const float*>(d_in[0]);
    const float* caps = reinterpret_cast<const float*>(d_in[1]);

    float* diag   = reinterpret_cast<float*>(d_ws);
    float* rowmax = diag + NN;
    float* colmax = rowmax + NN;
    short* imgsb  = reinterpret_cast<short*>(colmax + NN);
    short* capsb  = imgsb + (size_t)NN * DD;

    convert_kernel<<<(NN * DD / 8 + 255) / 256, 256, 0, stream>>>(imgs, imgsb);
    convert_kernel<<<(NN * DD / 8 + 255) / 256, 256, 0, stream>>>(caps, capsb);
    prep_kernel<<<NN, 64, 0, stream>>>(imgs, caps, diag, rowmax, colmax);

    score_max_kernel<<<512, 256, 0, stream>>>(imgsb, capsb, diag,
                                              rowmax, colmax);

    finalize_kernel<<<1, 256, 0, stream>>>(diag, rowmax, colmax,
                                           reinterpret_cast<float*>(d_out));
}

// Round 4
// 176.281 us; speedup vs baseline: 4.8746x; 1.0593x over previous
//
#include <hip/hip_runtime.h>
#include <hip/hip_bf16.h>
#include <stdint.h>
#include <math.h>

#define NN 16384
#define DD 256
#define MARGIN_F 0.2f

typedef __attribute__((ext_vector_type(8))) short bf16x8;
typedef __attribute__((ext_vector_type(4))) float f32x4;

__device__ inline short f2bf(float f) {
    __hip_bfloat16 h = __float2bfloat16(f);
    return *reinterpret_cast<short*>(&h);
}

__device__ inline void gload16(const void* g, void* l) {
    __builtin_amdgcn_global_load_lds(
        (const __attribute__((address_space(1))) void*)g,
        (__attribute__((address_space(3))) void*)l, 16, 0, 0);
}

// float atomic max via int/uint atomics (init = -inf)
__device__ inline void atomicMaxF(float* addr, float val) {
    if (val >= 0.0f) {
        atomicMax(reinterpret_cast<int*>(addr), __float_as_int(val));
    } else {
        atomicMin(reinterpret_cast<unsigned int*>(addr), __float_as_uint(val));
    }
}

// ---------------- fused prep: f32->bf16 + diag + init maxes ----------------
__global__ __launch_bounds__(64) void fused_prep_kernel(
    const float* __restrict__ imgs, const float* __restrict__ caps,
    short* __restrict__ imgsb, short* __restrict__ capsb,
    float* __restrict__ diag, float* __restrict__ rowmax,
    float* __restrict__ colmax) {
    const int i = blockIdx.x;
    const int l = threadIdx.x;  // 0..63, covers 256 elems as float4
    const float4* a4 = reinterpret_cast<const float4*>(imgs + (size_t)i * DD);
    const float4* b4 = reinterpret_cast<const float4*>(caps + (size_t)i * DD);
    float4 av = a4[l];
    float4 bv = b4[l];
    short4 as, bs;
    as.x = f2bf(av.x); as.y = f2bf(av.y); as.z = f2bf(av.z); as.w = f2bf(av.w);
    bs.x = f2bf(bv.x); bs.y = f2bf(bv.y); bs.z = f2bf(bv.z); bs.w = f2bf(bv.w);
    reinterpret_cast<short4*>(imgsb + (size_t)i * DD)[l] = as;
    reinterpret_cast<short4*>(capsb + (size_t)i * DD)[l] = bs;
    float s = av.x * bv.x + av.y * bv.y + av.z * bv.z + av.w * bv.w;
    #pragma unroll
    for (int off = 32; off > 0; off >>= 1) s += __shfl_down(s, off);
    if (l == 0) {
        diag[i] = s;
        rowmax[i] = -INFINITY;
        colmax[i] = -INFINITY;
    }
}

// ---------------- main: A-resident strip kernel, counted-vmcnt pipeline ----
// 512 blocks = 128 row-panels x 4 col-strips (4096 cols = 64 chunks of 64).
// A panel (128x256) staged once -> registers; B chunks double-buffered with
// T4 counted vmcnt (loads stay in flight across the h-boundary barriers).
__global__ __launch_bounds__(256, 2) void score_max_kernel(
    const short* __restrict__ imgsb, const short* __restrict__ capsb,
    const float* __restrict__ diag,
    float* __restrict__ rowmax, float* __restrict__ colmax) {

    __shared__ char lds[65536];   // A panel first, then 2x32KB B buffers

    const int bid   = blockIdx.x;
    const int panel = bid >> 2;
    const int strip = bid & 3;
    const int brow  = panel << 7;    // 128-row panel
    const int scol  = strip << 12;   // 4096-col strip

    const int t    = threadIdx.x;
    const int wid  = t >> 6;
    const int lane = t & 63;
    const int wr   = wid >> 1;   // 0..1: 64-row half
    const int wc   = wid & 1;    // 0..1: 32-col half of 64-col chunk
    const int rg   = lane >> 4;  // 0..3
    const int cl   = lane & 15;  // 0..15

    // ---- stage A panel: 128 rows x 32 slots of 16B, chunk-swizzled ----
    {
        const int cs = t & 31;       // slot within row
        const int r0 = t >> 5;       // base row 0..7
        const int co = ((cs ^ (r0 & 7)) << 3);   // (row&7) invariant across i
        const short* src = imgsb + (((size_t)(brow + r0)) << 8) + co;
        #pragma unroll
        for (int i = 0; i < 16; ++i)
            gload16(src + ((size_t)i << 11), lds + t * 16 + i * 4096);
    }
    __syncthreads();

    // ---- A fragments to registers: af[m][ks], 128 regs ----
    bf16x8 af[4][8];
    #pragma unroll
    for (int m = 0; m < 4; ++m) {
        const int row = wr * 64 + m * 16 + cl;
        const char* rb = lds + row * 512;
        const int sw = row & 7;
        #pragma unroll
        for (int ks = 0; ks < 8; ++ks) {
            const int k8 = (ks << 2) + rg;
            af[m][ks] = *reinterpret_cast<const bf16x8*>(rb + ((k8 ^ sw) << 4));
        }
    }
    __syncthreads();   // everyone done reading A before B overwrites

    // ---- B staging geometry (row&7 invariant across i) ----
    const int br0 = t >> 5;                       // 0..7
    const int bco = (((t & 31) ^ (br0 & 7)) << 3);

    #define STAGEB(bo, cb) {                                                   \
        const short* s_ = capsb + (((size_t)((cb) + br0)) << 8) + bco;         \
        _Pragma("unroll")                                                      \
        for (int i_ = 0; i_ < 8; ++i_)                                         \
            gload16(s_ + ((size_t)i_ << 11), lds + (bo) + t * 16 + i_ * 4096); \
    }

    float rmx[4][4];
    #pragma unroll
    for (int m = 0; m < 4; ++m)
        #pragma unroll
        for (int r = 0; r < 4; ++r) rmx[m][r] = -INFINITY;

    STAGEB(0, scol);   // prologue: stage h=0

    for (int h = 0; h < 64; ++h) {
        const int cb = scol + h * 64;
        const char* cur = lds + ((h & 1) << 15);

        // barrier 1: all waves finished reading buf[(h+1)&1] (during h-1)
        __builtin_amdgcn_s_barrier();
        asm volatile("" ::: "memory");
        if (h + 1 < 64) {
            STAGEB(((h + 1) & 1) << 15, cb + 64);
            // wait for stage(h)'s 8 loads (and everything older); the 8
            // newest (stage h+1) stay in flight across the whole h body.
            asm volatile("s_waitcnt vmcnt(8)" ::: "memory");
        } else {
            asm volatile("s_waitcnt vmcnt(0)" ::: "memory");
        }
        // barrier 2: all waves' cur-chunk loads have landed in LDS
        __builtin_amdgcn_s_barrier();
        asm volatile("" ::: "memory");

        f32x4 acc[4][2];
        #pragma unroll
        for (int m = 0; m < 4; ++m) {
            acc[m][0] = (f32x4){0.f, 0.f, 0.f, 0.f};
            acc[m][1] = (f32x4){0.f, 0.f, 0.f, 0.f};
        }

        __builtin_amdgcn_s_setprio(1);
        #pragma unroll
        for (int ks = 0; ks < 8; ++ks) {
            const int k8 = (ks << 2) + rg;
            const int r0 = wc * 32 + cl;        // n=0 col-row
            const int r1 = r0 + 16;             // n=1 col-row
            bf16x8 bf0 = *reinterpret_cast<const bf16x8*>(
                cur + r0 * 512 + ((k8 ^ (r0 & 7)) << 4));
            bf16x8 bf1 = *reinterpret_cast<const bf16x8*>(
                cur + r1 * 512 + ((k8 ^ (r1 & 7)) << 4));
            #pragma unroll
            for (int m = 0; m < 4; ++m) {
                acc[m][0] = __builtin_amdgcn_mfma_f32_16x16x32_bf16(
                    af[m][ks], bf0, acc[m][0], 0, 0, 0);
                acc[m][1] = __builtin_amdgcn_mfma_f32_16x16x32_bf16(
                    af[m][ks], bf1, acc[m][1], 0, 0, 0);
            }
        }
        __builtin_amdgcn_s_setprio(0);

        // ---- diagonal fix (at most 2 chunks per block) ----
        if (cb < brow + 128 && cb + 64 > brow) {
            #pragma unroll
            for (int m = 0; m < 4; ++m)
                #pragma unroll
                for (int r = 0; r < 4; ++r) {
                    const int i = brow + wr * 64 + m * 16 + (rg << 2) + r;
                    const int d = i - cb - wc * 32;
                    #pragma unroll
                    for (int n = 0; n < 2; ++n)
                        if (d == n * 16 + cl) acc[m][n][r] = -diag[i];
                }
        }

        // ---- running row-max (registers, no shuffles) ----
        #pragma unroll
        for (int m = 0; m < 4; ++m)
            #pragma unroll
            for (int r = 0; r < 4; ++r)
                rmx[m][r] = fmaxf(rmx[m][r],
                                  fmaxf(acc[m][0][r], acc[m][1][r]));

        // ---- col-max for this chunk ----
        #pragma unroll
        for (int n = 0; n < 2; ++n) {
            float v = acc[0][n][0];
            #pragma unroll
            for (int m = 0; m < 4; ++m)
                #pragma unroll
                for (int r = 0; r < 4; ++r)
                    v = fmaxf(v, acc[m][n][r]);
            v = fmaxf(v, __shfl_xor(v, 16));
            v = fmaxf(v, __shfl_xor(v, 32));
            if (rg == 0)
                atomicMaxF(&colmax[cb + wc * 32 + n * 16 + cl], v);
        }
    }

    // ---- row-max writeout (once per block) ----
    #pragma unroll
    for (int m = 0; m < 4; ++m)
        #pragma unroll
        for (int r = 0; r < 4; ++r) {
            float v = rmx[m][r];
            v = fmaxf(v, __shfl_xor(v, 1));
            v = fmaxf(v, __shfl_xor(v, 2));
            v = fmaxf(v, __shfl_xor(v, 4));
            v = fmaxf(v, __shfl_xor(v, 8));
            if (cl == 0)
                atomicMaxF(&rowmax[brow + wr * 64 + m * 16 + (rg << 2) + r], v);
        }
    #undef STAGEB
}

// ---------------- finalize: hinge + total sum ----------------
__global__ void finalize_kernel(const float* __restrict__ diag,
                                const float* __restrict__ rowmax,
                                const float* __restrict__ colmax,
                                float* __restrict__ out) {
    __shared__ float red[256];
    int t = threadIdx.x;
    float s = 0.f;
    for (int idx = t; idx < 2 * NN; idx += 256) {
        int i = idx & (NN - 1);
        float mx = (idx < NN) ? colmax[i] : rowmax[i];
        s += fmaxf(mx + (MARGIN_F - diag[i]), 0.f);
    }
    red[t] = s;
    __syncthreads();
    for (int off = 128; off > 0; off >>= 1) {
        if (t < off) red[t] += red[t + off];
        __syncthreads();
    }
    if (t == 0) out[0] = red[0];
}

extern "C" void kernel_launch(void* const* d_in, const int* in_sizes, int n_in,
                              void* d_out, int out_size, void* d_ws, size_t ws_size,
                              hipStream_t stream) {
    const float* imgs = reinterpret_cast<const float*>(d_in[0]);
    const float* caps = reinterpret_cast<const float*>(d_in[1]);

    float* diag   = reinterpret_cast<float*>(d_ws);
    float* rowmax = diag + NN;
    float* colmax = rowmax + NN;
    short* imgsb  = reinterpret_cast<short*>(colmax + NN);
    short* capsb  = imgsb + (size_t)NN * DD;

    fused_prep_kernel<<<NN, 64, 0, stream>>>(imgs, caps, imgsb, capsb,
                                             diag, rowmax, colmax);

    score_max_kernel<<<512, 256, 0, stream>>>(imgsb, capsb, diag,
                                              rowmax, colmax);

    finalize_kernel<<<1, 256, 0, stream>>>(diag, rowmax, colmax,
                                           reinterpret_cast<float*>(d_out));
}